// Round 13
// baseline (311.234 us; speedup 1.0000x reference)
//
#include <hip/hip_runtime.h>
#include <hip/hip_cooperative_groups.h>

namespace cg = cooperative_groups;

#define A_N 192
#define D_N 576
#define W_N 384
#define NPIX (W_N * W_N)   // 147456
#define NSIN (A_N * D_N)   // 110592
#define RSTR 580           // padded inter row stride (float2 units)

// ============================================================================
// Shared device bodies (used by both the fused cooperative kernel and the
// 3-kernel fallback path).
// ============================================================================

// conv2(conv1(x)) == 81-tap collapsed class kernel on a zero-padded tile; the
// conv2 q-mask depends only on the pixel's edge-distance class. Block 0 also
// writes tab[a]=(cb,sb,u,v) and the inter guard cells (d=-2,-1,576,577).
__device__ __forceinline__ void conv9_body(
    int bid, int tid,
    const float* __restrict__ sino, const float* __restrict__ angles,
    const float* __restrict__ w1, const float* __restrict__ b1,
    const float* __restrict__ w2, const float* __restrict__ b2,
    float* __restrict__ sino_pred, float2* __restrict__ inter,
    float4* __restrict__ tab,
    float (*t)[40], float* sw1, float* sw2, float* sb1,
    float* K, float* wsb1, float (*Wcs)[81], float* biasc)
{
    int byi = bid / 18;
    int bxi = bid % 18;
    int y0 = byi * 8, x0 = bxi * 32;

    if (bid == 0) {
        if (tid < A_N) {
            float s, c;
            sincosf(angles[tid], &s, &c);
            tab[tid] = make_float4(c, s, fmaf(576.f, c, -287.5f * s),
                                         fmaf(576.f, s,  287.5f * c));
        }
        for (int i = tid; i < A_N * 4; i += 256) {
            int a = i >> 2, j = i & 3;
            inter[a * RSTR + (j < 2 ? j : 576 + j)] = make_float2(0.f, 0.f);
        }
    }

    for (int i = tid; i < 640; i += 256) {
        int r = i / 40, c = i - r * 40;
        int gy = y0 - 4 + r, gx = x0 - 4 + c;
        t[r][c] = (gy >= 0 && gy < A_N && gx >= 0 && gx < D_N)
                ? sino[gy * D_N + gx] : 0.f;
    }
    for (int i = tid; i < 400; i += 256) { sw1[i] = w1[i]; sw2[i] = w2[i]; }
    if (tid < 16) sb1[tid] = b1[tid];
    __syncthreads();

    for (int i = tid; i < 625; i += 256) {
        int q = i / 25, r = i - q * 25;
        float acc = 0.f;
        #pragma unroll
        for (int c = 0; c < 16; ++c)
            acc = fmaf(sw2[c * 25 + q], sw1[c * 25 + r], acc);
        K[i] = acc;
    }
    if (tid < 25) {
        float acc = 0.f;
        #pragma unroll
        for (int c = 0; c < 16; ++c) acc = fmaf(sw2[c * 25 + tid], sb1[c], acc);
        wsb1[tid] = acc;
    }
    __syncthreads();

    int ylo = (y0 == 0) ? 0 : 2, yhi = (y0 == A_N - 8) ? 4 : 2;
    int xlo = (x0 == 0) ? 0 : 2, xhi = (x0 == D_N - 32) ? 4 : 2;
    int nx = xhi - xlo + 1;
    int nc = (yhi - ylo + 1) * nx;

    for (int e = tid; e < nc * 81; e += 256) {
        int ci = e / 81, s = e - ci * 81;
        int yc = ylo + ci / nx, xc = xlo + ci % nx;
        int sy = s / 9 - 4, sx = s % 9 - 4;
        float acc = 0.f;
        for (int qy = -2; qy <= 2; ++qy) {
            if ((yc == 0 && qy < 0) || (yc == 1 && qy < -1) ||
                (yc == 3 && qy > 1) || (yc == 4 && qy > 0)) continue;
            int vy = sy - qy; if (vy < -2 || vy > 2) continue;
            for (int qx = -2; qx <= 2; ++qx) {
                if ((xc == 0 && qx < 0) || (xc == 1 && qx < -1) ||
                    (xc == 3 && qx > 1) || (xc == 4 && qx > 0)) continue;
                int vx = sx - qx; if (vx < -2 || vx > 2) continue;
                acc += K[((qy + 2) * 5 + qx + 2) * 25 + (vy + 2) * 5 + (vx + 2)];
            }
        }
        Wcs[ci][s] = acc;
    }
    if (tid < nc) {
        int yc = ylo + tid / nx, xc = xlo + tid % nx;
        float acc = b2[0];
        for (int qy = -2; qy <= 2; ++qy) {
            if ((yc == 0 && qy < 0) || (yc == 1 && qy < -1) ||
                (yc == 3 && qy > 1) || (yc == 4 && qy > 0)) continue;
            for (int qx = -2; qx <= 2; ++qx) {
                if ((xc == 0 && qx < 0) || (xc == 1 && qx < -1) ||
                    (xc == 3 && qx > 1) || (xc == 4 && qx > 0)) continue;
                acc += wsb1[(qy + 2) * 5 + qx + 2];
            }
        }
        biasc[tid] = acc;
    }
    __syncthreads();

    int lr = tid >> 5, lc = tid & 31;
    int gy = y0 + lr, gx = x0 + lc;
    int yc = (gy <= 1) ? gy : ((gy >= A_N - 2) ? (gy - (A_N - 5)) : 2);
    int xc = (gx <= 1) ? gx : ((gx >= D_N - 2) ? (gx - (D_N - 5)) : 2);
    int ci = (yc - ylo) * nx + (xc - xlo);
    float acc = biasc[ci];
    const float* Wp = Wcs[ci];
    #pragma unroll
    for (int sy = 0; sy < 9; ++sy)
        #pragma unroll
        for (int sx = 0; sx < 9; ++sx)
            acc = fmaf(t[lr + sy][lc + sx], Wp[sy * 9 + sx], acc);
    sino_pred[gy * D_N + gx] = acc;
    inter[gy * RSTR + 2 + gx] = make_float2(t[lr + 4][lc + 4], acc);
}

// Branch-free dual backprojection inner loop over nA angles starting at a0.
__device__ __forceinline__ void bp_body(
    int gx, int gy, int a0, int nA,
    const float2* __restrict__ inter, const float4* __restrict__ tab,
    float& acc0, float& acc1)
{
    float X = (float)gx - 191.5f;
    float Y = (float)gy - 191.5f;
    const float2* base = inter + (size_t)a0 * RSTR + 2;
    #pragma unroll 8
    for (int i = 0; i < nA; ++i) {
        float4 tb = tab[a0 + i];           // uniform -> scalar loads
        float den = fmaf(tb.x, Y, fmaf(-tb.y, X, 576.f));
        float num = fmaf(tb.z, X, fmaf(tb.w, Y, 165600.f));
        float s   = num * __builtin_amdgcn_rcpf(den);
        float sc  = fminf(fmaxf(s, -2.f), 576.f);   // v_med3_f32
        float fl  = floorf(sc);
        float fr  = sc - fl;
        int   ic  = (int)fl;
        float4 v = *reinterpret_cast<const float4*>(base + (size_t)i * RSTR + ic);
        acc0 = fmaf(v.x, 1.f - fr, fmaf(v.z, fr, acc0));
        acc1 = fmaf(v.y, 1.f - fr, fmaf(v.w, fr, acc1));
    }
}

// conv3 over summed partial planes (nP planes of float2 (img, img_sino)).
__device__ __forceinline__ void conv3_body(
    int bid, int tid, int nP,
    const float2* __restrict__ part2,
    const float* __restrict__ w3, const float* __restrict__ b3,
    float* __restrict__ img_sino, float* __restrict__ img_pred,
    float (*t0)[34], float (*t1)[34], float* sw)
{
    int byi = bid / 12, bxi = bid % 12;
    int y0 = byi * 8, x0 = bxi * 32;
    for (int i = tid; i < 340; i += 256) {
        int r = i / 34, c = i - r * 34;
        int gy = y0 - 1 + r, gx = x0 - 1 + c;
        float s0 = 0.f, s1 = 0.f;
        if (gy >= 0 && gy < W_N && gx >= 0 && gx < W_N) {
            int g = gy * W_N + gx;
            for (int p = 0; p < nP; ++p) {
                float2 v = part2[p * NPIX + g];
                s0 += v.x; s1 += v.y;
            }
        }
        t0[r][c] = s0; t1[r][c] = s1;
    }
    if (tid < 18) sw[tid] = w3[tid];
    __syncthreads();
    int lr = tid >> 5, lc = tid & 31;
    int gy = y0 + lr, gx = x0 + lc;
    int g = gy * W_N + gx;
    img_sino[g] = t1[lr + 1][lc + 1];
    float acc = b3[0];
    #pragma unroll
    for (int dy = 0; dy < 3; ++dy)
        #pragma unroll
        for (int dx = 0; dx < 3; ++dx) {
            acc = fmaf(t0[lr + dy][lc + dx], sw[dy * 3 + dx], acc);
            acc = fmaf(t1[lr + dy][lc + dx], sw[9 + dy * 3 + dx], acc);
        }
    img_pred[g] = acc;
}

// ============================================================================
// Fused cooperative kernel: conv9 -> grid.sync -> bp(all) -> grid.sync -> conv3
// 1152 blocks x 256 threads; __launch_bounds__(256,5) guarantees >=5 blocks/CU
// so the cooperative launch (all-co-resident) is valid on 256 CUs.
// ============================================================================
__global__ __launch_bounds__(256, 5) void fused_kernel(
    const float* __restrict__ sino, const float* __restrict__ angles,
    const float* __restrict__ w1, const float* __restrict__ b1,
    const float* __restrict__ w2, const float* __restrict__ b2,
    const float* __restrict__ w3, const float* __restrict__ b3,
    float* __restrict__ sino_pred, float* __restrict__ img_sino,
    float* __restrict__ img_pred,
    float2* __restrict__ inter, float4* __restrict__ tab,
    float2* __restrict__ part2)
{
    cg::grid_group grid = cg::this_grid();
    int tid = threadIdx.x;
    int bid = blockIdx.x;

    __shared__ float t[16][40];
    __shared__ float sw1[400], sw2[400], sb1[16];
    __shared__ float K[625], wsb1[25];
    __shared__ float Wcs[9][81];
    __shared__ float biasc[9];
    __shared__ float t0s[10][34], t1s[10][34];
    __shared__ float sw3[18];

    // phase 0: conv9 on blocks 0..431 (others wait at the sync)
    if (bid < 432)
        conv9_body(bid, tid, sino, angles, w1, b1, w2, b2,
                   sino_pred, inter, tab,
                   t, sw1, sw2, sb1, K, wsb1, Wcs, biasc);
    grid.sync();

    // phase 1: backprojection on ALL 1152 blocks (seg x2, 96 angles each)
    {
        int seg  = (bid >= 576) ? 1 : 0;
        int tile = bid - seg * 576;
        int a0   = seg * 96;
        int gx = (tile % 24) * 16 + (tid & 15);
        int gy = (tile / 24) * 16 + (tid >> 4);
        float acc0 = 0.f, acc1 = 0.f;
        bp_body(gx, gy, a0, 96, inter, tab, acc0, acc1);
        part2[seg * NPIX + gy * W_N + gx] = make_float2(acc0, acc1);
    }
    grid.sync();

    // phase 2: conv3 on blocks 0..575
    if (bid < 576)
        conv3_body(bid, tid, 2, part2, w3, b3, img_sino, img_pred,
                   t0s, t1s, sw3);
}

// ============================================================================
// Fallback path (r12-proven 3-kernel pipeline), used only if the cooperative
// launch is rejected (e.g. capture incompatibility).
// ============================================================================
__global__ __launch_bounds__(256) void conv9_kernel(
    const float* __restrict__ sino, const float* __restrict__ angles,
    const float* __restrict__ w1, const float* __restrict__ b1,
    const float* __restrict__ w2, const float* __restrict__ b2,
    float* __restrict__ sino_pred, float2* __restrict__ inter,
    float4* __restrict__ tab)
{
    __shared__ float t[16][40];
    __shared__ float sw1[400], sw2[400], sb1[16];
    __shared__ float K[625], wsb1[25];
    __shared__ float Wcs[9][81];
    __shared__ float biasc[9];
    conv9_body(blockIdx.x, threadIdx.x, sino, angles, w1, b1, w2, b2,
               sino_pred, inter, tab, t, sw1, sw2, sb1, K, wsb1, Wcs, biasc);
}

__global__ __launch_bounds__(256) void backproject2_kernel(
    const float2* __restrict__ inter, const float4* __restrict__ tab,
    float2* __restrict__ part2)
{
    int tid = threadIdx.x;
    int seg = blockIdx.z;                  // 0..2
    int a0 = seg * 64;
    int gx = blockIdx.x * 16 + (tid & 15);
    int gy = blockIdx.y * 16 + (tid >> 4);
    float acc0 = 0.f, acc1 = 0.f;
    bp_body(gx, gy, a0, 64, inter, tab, acc0, acc1);
    part2[seg * NPIX + gy * W_N + gx] = make_float2(acc0, acc1);
}

__global__ __launch_bounds__(256) void conv3_kernel(
    const float2* __restrict__ part2,
    const float* __restrict__ w3, const float* __restrict__ b3,
    float* __restrict__ img_sino, float* __restrict__ img_pred)
{
    __shared__ float t0s[10][34], t1s[10][34];
    __shared__ float sw3[18];
    conv3_body(blockIdx.x, threadIdx.x, 3, part2, w3, b3,
               img_sino, img_pred, t0s, t1s, sw3);
}

extern "C" void kernel_launch(void* const* d_in, const int* in_sizes, int n_in,
                              void* d_out, int out_size, void* d_ws, size_t ws_size,
                              hipStream_t stream) {
    const float* sino   = (const float*)d_in[0];
    const float* angles = (const float*)d_in[1];
    const float* w1     = (const float*)d_in[2];
    const float* b1     = (const float*)d_in[3];
    const float* w2     = (const float*)d_in[4];
    const float* b2     = (const float*)d_in[5];
    const float* w3     = (const float*)d_in[6];
    const float* b3     = (const float*)d_in[7];

    float* out       = (float*)d_out;
    float* sino_pred = out;                       // 110592
    float* img_sino  = out + NSIN;                // 147456
    float* img_pred  = img_sino + NPIX;           // 147456

    float2* inter = (float2*)d_ws;                          // 192*580 float2
    float4* tab   = (float4*)((char*)d_ws + (size_t)A_N * RSTR * sizeof(float2));
    float2* part2 = (float2*)((char*)tab + A_N * sizeof(float4)); // 3*NPIX float2

    void* args[] = {
        (void*)&sino, (void*)&angles,
        (void*)&w1, (void*)&b1, (void*)&w2, (void*)&b2,
        (void*)&w3, (void*)&b3,
        (void*)&sino_pred, (void*)&img_sino, (void*)&img_pred,
        (void*)&inter, (void*)&tab, (void*)&part2
    };
    hipError_t err = hipLaunchCooperativeKernel(
        fused_kernel, dim3(1152), dim3(256), args, 0u, stream);

    if (err != hipSuccess) {
        (void)hipGetLastError();   // clear sticky error, use fallback path
        conv9_kernel<<<dim3(432), dim3(256), 0, stream>>>(
            sino, angles, w1, b1, w2, b2, sino_pred, inter, tab);
        backproject2_kernel<<<dim3(24, 24, 3), dim3(256), 0, stream>>>(
            inter, tab, part2);
        conv3_kernel<<<dim3(576), dim3(256), 0, stream>>>(
            part2, w3, b3, img_sino, img_pred);
    }
}

// Round 14
// 34.071 us; speedup vs baseline: 9.1348x; 9.1348x over previous
//
#include <hip/hip_runtime.h>

#define A_N 192
#define D_N 576
#define W_N 384
#define NPIX (W_N * W_N)   // 147456
#define NSIN (A_N * D_N)   // 110592
#define RSTR 580           // padded inter row stride (float2 units)

// ---- fused conv1+conv2 via on-demand boundary-class collapsed 9x9 kernels --
// conv2(conv1(x)) == 81-tap collapsed kernel on a zero-padded input tile,
// except for the conv2 q-mask [p+q in domain], which depends only on the
// pixel's edge-distance class. A tile only contains classes yc in [ylo,yhi],
// xc in [xlo,xhi] (interior blocks: exactly one), so compute only those.
// Writes inter[a*580+2+d] = (sino, sino_pred) interleaved (stride-580 rows,
// zero guard cells at d=-2,-1,576,577 so the backprojection needs no mask).
// Block 0 additionally fills the per-angle table tab[a]=(cb,sb,u,v) and the
// guard cells.
// __launch_bounds__(256, 1): allow up to 256 VGPR so the compiler can keep
// many of the 162 LDS reads/px in flight (at VGPR=24 it serialized on LDS
// latency; grid is 1.7 blocks/CU so occupancy is grid-limited regardless).
__global__ __launch_bounds__(256, 1) void conv9_kernel(
    const float* __restrict__ sino, const float* __restrict__ angles,
    const float* __restrict__ w1, const float* __restrict__ b1,
    const float* __restrict__ w2, const float* __restrict__ b2,
    float* __restrict__ sino_pred, float2* __restrict__ inter,
    float4* __restrict__ tab)
{
    __shared__ float t[16][40];            // zero-padded 8x32 tile + 4 halo
    __shared__ float sw1[400], sw2[400], sb1[16];
    __shared__ float K[625], wsb1[25];
    __shared__ float Wcs[9][81];           // on-demand class kernels
    __shared__ float biasc[9];

    int tid = threadIdx.x;
    int byi = blockIdx.x / 18;             // 576/32 = 18 tiles in x
    int bxi = blockIdx.x % 18;
    int y0 = byi * 8, x0 = bxi * 32;

    if (blockIdx.x == 0) {                 // per-angle table + guard cells
        if (tid < A_N) {
            float s, c;
            sincosf(angles[tid], &s, &c);
            tab[tid] = make_float4(c, s, fmaf(576.f, c, -287.5f * s),
                                         fmaf(576.f, s,  287.5f * c));
        }
        for (int i = tid; i < A_N * 4; i += 256) {
            int a = i >> 2, j = i & 3;
            inter[a * RSTR + (j < 2 ? j : 576 + j)] = make_float2(0.f, 0.f);
        }
    }

    for (int i = tid; i < 640; i += 256) {
        int r = i / 40, c = i - r * 40;
        int gy = y0 - 4 + r, gx = x0 - 4 + c;
        t[r][c] = (gy >= 0 && gy < A_N && gx >= 0 && gx < D_N)
                ? sino[gy * D_N + gx] : 0.f;
    }
    for (int i = tid; i < 400; i += 256) { sw1[i] = w1[i]; sw2[i] = w2[i]; }
    if (tid < 16) sb1[tid] = b1[tid];
    __syncthreads();

    for (int i = tid; i < 625; i += 256) {
        int q = i / 25, r = i - q * 25;
        float acc = 0.f;
        #pragma unroll
        for (int c = 0; c < 16; ++c)
            acc = fmaf(sw2[c * 25 + q], sw1[c * 25 + r], acc);
        K[i] = acc;
    }
    if (tid < 25) {
        float acc = 0.f;
        #pragma unroll
        for (int c = 0; c < 16; ++c) acc = fmaf(sw2[c * 25 + tid], sb1[c], acc);
        wsb1[tid] = acc;
    }
    __syncthreads();

    int ylo = (y0 == 0) ? 0 : 2, yhi = (y0 == A_N - 8) ? 4 : 2;
    int xlo = (x0 == 0) ? 0 : 2, xhi = (x0 == D_N - 32) ? 4 : 2;
    int nx = xhi - xlo + 1;
    int nc = (yhi - ylo + 1) * nx;

    for (int e = tid; e < nc * 81; e += 256) {
        int ci = e / 81, s = e - ci * 81;
        int yc = ylo + ci / nx, xc = xlo + ci % nx;
        int sy = s / 9 - 4, sx = s % 9 - 4;
        float acc = 0.f;
        for (int qy = -2; qy <= 2; ++qy) {
            if ((yc == 0 && qy < 0) || (yc == 1 && qy < -1) ||
                (yc == 3 && qy > 1) || (yc == 4 && qy > 0)) continue;
            int vy = sy - qy; if (vy < -2 || vy > 2) continue;
            for (int qx = -2; qx <= 2; ++qx) {
                if ((xc == 0 && qx < 0) || (xc == 1 && qx < -1) ||
                    (xc == 3 && qx > 1) || (xc == 4 && qx > 0)) continue;
                int vx = sx - qx; if (vx < -2 || vx > 2) continue;
                acc += K[((qy + 2) * 5 + qx + 2) * 25 + (vy + 2) * 5 + (vx + 2)];
            }
        }
        Wcs[ci][s] = acc;
    }
    if (tid < nc) {
        int yc = ylo + tid / nx, xc = xlo + tid % nx;
        float acc = b2[0];
        for (int qy = -2; qy <= 2; ++qy) {
            if ((yc == 0 && qy < 0) || (yc == 1 && qy < -1) ||
                (yc == 3 && qy > 1) || (yc == 4 && qy > 0)) continue;
            for (int qx = -2; qx <= 2; ++qx) {
                if ((xc == 0 && qx < 0) || (xc == 1 && qx < -1) ||
                    (xc == 3 && qx > 1) || (xc == 4 && qx > 0)) continue;
                acc += wsb1[(qy + 2) * 5 + qx + 2];
            }
        }
        biasc[tid] = acc;
    }
    __syncthreads();

    int lr = tid >> 5, lc = tid & 31;
    int gy = y0 + lr, gx = x0 + lc;
    int yc = (gy <= 1) ? gy : ((gy >= A_N - 2) ? (gy - (A_N - 5)) : 2);
    int xc = (gx <= 1) ? gx : ((gx >= D_N - 2) ? (gx - (D_N - 5)) : 2);
    int ci = (yc - ylo) * nx + (xc - xlo);
    float acc = biasc[ci];
    const float* Wp = Wcs[ci];
    #pragma unroll
    for (int sy = 0; sy < 9; ++sy)
        #pragma unroll
        for (int sx = 0; sx < 9; ++sx)
            acc = fmaf(t[lr + sy][lc + sx], Wp[sy * 9 + sx], acc);
    sino_pred[gy * D_N + gx] = acc;
    inter[gy * RSTR + 2 + gx] = make_float2(t[lr + 4][lc + 4], acc);
}

// ---- dual fan-beam backprojection, 16x16 tiles, angle-split x3 -------------
// 1728 blocks of 4 waves = 6.75 blocks/CU -> entire grid co-resident in ONE
// scheduling batch (8-block/CU cap), no straggler batch.
// s = num/den; float clamp sc = med3(s,-2,576); guard zeros at d=-2,-1,576,
// 577 make out-of-range taps contribute 0 with no masking. One float4 gather
// covers both interp taps of both sinograms; unroll 8 for MLP.
// part2 layout: [seg][NPIX] float2 = (img, img_sino) partial sums.
__global__ __launch_bounds__(256) void backproject2_kernel(
    const float2* __restrict__ inter, const float4* __restrict__ tab,
    float2* __restrict__ part2)
{
    int tid = threadIdx.x;
    int seg = blockIdx.z;                  // 0..2
    int a0 = seg * 64;
    int tx = tid & 15, ty = tid >> 4;
    int gx = blockIdx.x * 16 + tx;
    int gy = blockIdx.y * 16 + ty;
    int idx = gy * W_N + gx;
    float X = (float)gx - 191.5f;
    float Y = (float)gy - 191.5f;
    float acc0 = 0.f, acc1 = 0.f;
    const float2* base = inter + (size_t)a0 * RSTR + 2;
    #pragma unroll 8
    for (int i = 0; i < 64; ++i) {
        float4 tb = tab[a0 + i];           // uniform -> scalar loads
        float den = fmaf(tb.x, Y, fmaf(-tb.y, X, 576.f));
        float num = fmaf(tb.z, X, fmaf(tb.w, Y, 165600.f));
        float s   = num * __builtin_amdgcn_rcpf(den);
        float sc  = fminf(fmaxf(s, -2.f), 576.f);   // v_med3_f32
        float fl  = floorf(sc);
        float fr  = sc - fl;
        int   ic  = (int)fl;
        float4 v = *reinterpret_cast<const float4*>(base + (size_t)i * RSTR + ic);
        acc0 = fmaf(v.x, 1.f - fr, fmaf(v.z, fr, acc0));
        acc1 = fmaf(v.y, 1.f - fr, fmaf(v.w, fr, acc1));
    }
    part2[seg * NPIX + idx] = make_float2(acc0, acc1);
}

// ---- fused partial-sum (x3) + conv3: writes img_sino and img_pred ----------
__global__ __launch_bounds__(256) void conv3_kernel(
    const float2* __restrict__ part2,
    const float* __restrict__ w3, const float* __restrict__ b3,
    float* __restrict__ img_sino, float* __restrict__ img_pred)
{
    __shared__ float t0[10][34], t1[10][34];
    __shared__ float sw[18];
    int tid = threadIdx.x;
    int byi = blockIdx.x / 12, bxi = blockIdx.x % 12;   // 384/32=12, 384/8=48
    int y0 = byi * 8, x0 = bxi * 32;
    for (int i = tid; i < 340; i += 256) {
        int r = i / 34, c = i - r * 34;
        int gy = y0 - 1 + r, gx = x0 - 1 + c;
        float s0 = 0.f, s1 = 0.f;
        if (gy >= 0 && gy < W_N && gx >= 0 && gx < W_N) {
            int g = gy * W_N + gx;
            #pragma unroll
            for (int p = 0; p < 3; ++p) {
                float2 v = part2[p * NPIX + g];
                s0 += v.x; s1 += v.y;
            }
        }
        t0[r][c] = s0; t1[r][c] = s1;
    }
    if (tid < 18) sw[tid] = w3[tid];
    __syncthreads();
    int lr = tid >> 5, lc = tid & 31;
    int gy = y0 + lr, gx = x0 + lc;
    int g = gy * W_N + gx;
    img_sino[g] = t1[lr + 1][lc + 1];
    float acc = b3[0];
    #pragma unroll
    for (int dy = 0; dy < 3; ++dy)
        #pragma unroll
        for (int dx = 0; dx < 3; ++dx) {
            acc = fmaf(t0[lr + dy][lc + dx], sw[dy * 3 + dx], acc);
            acc = fmaf(t1[lr + dy][lc + dx], sw[9 + dy * 3 + dx], acc);
        }
    img_pred[g] = acc;
}

extern "C" void kernel_launch(void* const* d_in, const int* in_sizes, int n_in,
                              void* d_out, int out_size, void* d_ws, size_t ws_size,
                              hipStream_t stream) {
    const float* sino   = (const float*)d_in[0];
    const float* angles = (const float*)d_in[1];
    const float* w1     = (const float*)d_in[2];
    const float* b1     = (const float*)d_in[3];
    const float* w2     = (const float*)d_in[4];
    const float* b2     = (const float*)d_in[5];
    const float* w3     = (const float*)d_in[6];
    const float* b3     = (const float*)d_in[7];

    float* out       = (float*)d_out;
    float* sino_pred = out;                       // 110592
    float* img_sino  = out + NSIN;                // 147456
    float* img_pred  = img_sino + NPIX;           // 147456

    float2* inter = (float2*)d_ws;                          // 192*580 float2
    float4* tab   = (float4*)((char*)d_ws + (size_t)A_N * RSTR * sizeof(float2));
    float2* part2 = (float2*)((char*)tab + A_N * sizeof(float4)); // 3*NPIX float2

    conv9_kernel<<<dim3(432), dim3(256), 0, stream>>>(
        sino, angles, w1, b1, w2, b2, sino_pred, inter, tab);
    backproject2_kernel<<<dim3(24, 24, 3), dim3(256), 0, stream>>>(
        inter, tab, part2);
    conv3_kernel<<<dim3(576), dim3(256), 0, stream>>>(
        part2, w3, b3, img_sino, img_pred);
}